// Round 2
// baseline (833.831 us; speedup 1.0000x reference)
//
#include <hip/hip_runtime.h>
#include <cstdint>
#include <cmath>

#define NB 64
#define NS 2048
#define NR 1024
#define NH 512
#define SC 32              // s-chunks in weighted-sum kernel
#define SCHUNK (NS / SC)   // 64

__device__ __forceinline__ float waveReduceSum(float v) {
    #pragma unroll
    for (int off = 32; off > 0; off >>= 1) v += __shfl_down(v, off, 64);
    return v;
}

__device__ __forceinline__ float fast_tanh(float x) {
    // tanh(x) = (e^{2x}-1)/(e^{2x}+1); clamp so exp never overflows.
    float cx = fminf(fmaxf(x, -15.f), 15.f);
    float e = __expf(2.f * cx);
    return __fdividef(e - 1.f, e + 1.f);
}

// ---------------- Kernel 1: att_h[b,o] = sum_k h[b,k]*W[o,k] + bias[o] ----------------
__global__ __launch_bounds__(256) void k_atth(
    const float* __restrict__ h, const float* __restrict__ W,
    const float* __restrict__ bias, float* __restrict__ att_h)
{
    const int o = blockIdx.x;  // 0..NH-1
    __shared__ float wsh[NR];
    for (int i = threadIdx.x; i < NR; i += 256) wsh[i] = W[(size_t)o * NR + i];
    __syncthreads();
    const int wave = threadIdx.x >> 6, lane = threadIdx.x & 63;
    const float4* w4 = (const float4*)wsh;
    const float bo = bias[o];
    for (int b = wave; b < NB; b += 4) {
        const float4* h4 = (const float4*)(h + (size_t)b * NR);
        float acc = 0.f;
        #pragma unroll
        for (int i = 0; i < NR / 4 / 64; ++i) {  // 4 iters
            float4 a = h4[lane + i * 64];
            float4 w = w4[lane + i * 64];
            acc += a.x * w.x + a.y * w.y + a.z * w.z + a.w * w.w;
        }
        acc = waveReduceSum(acc);
        if (lane == 0) att_h[b * NH + o] = acc + bo;
    }
}

// ---------------- Kernel 2: unnormalized masked-softmax weights + per-batch sum -------
// b_alpha cancels in the softmax ratio; scores are O(few), so no max-subtraction needed.
// weights[b,s] = mask ? exp(score) : 0 ;  sums[b] += weights[b,s]
__global__ __launch_bounds__(256) void k_scores(
    const float* __restrict__ p, const float* __restrict__ att_h,
    const float* __restrict__ w_alpha,
    const int* __restrict__ masks, float* __restrict__ weights,
    float* __restrict__ sums)
{
    const int b = blockIdx.x >> 7;                 // 128 blocks per batch
    const int s_base = (blockIdx.x & 127) << 4;    // 16 s-rows per block
    const int wave = threadIdx.x >> 6, lane = threadIdx.x & 63;
    __shared__ float ah[NH], wa[NH];
    __shared__ float blksum;
    if (threadIdx.x == 0) blksum = 0.f;
    for (int i = threadIdx.x; i < NH; i += 256) {
        ah[i] = att_h[b * NH + i];
        wa[i] = w_alpha[i];
    }
    __syncthreads();
    const float4* ah4 = (const float4*)ah;
    const float4* wa4 = (const float4*)wa;
    float esum = 0.f;
    #pragma unroll
    for (int j = 0; j < 4; ++j) {                  // 4 s-rows per wave
        const int s = s_base + (wave << 2) + j;
        const int sidx = b * NS + s;
        if (masks[sidx] == 0) {                    // wave-uniform: p row never fetched
            if (lane == 0) weights[sidx] = 0.f;
            continue;
        }
        const float4* p4 = (const float4*)(p + (size_t)sidx * NH);
        float acc = 0.f;
        #pragma unroll
        for (int i = 0; i < 2; ++i) {
            float4 x = p4[lane + i * 64];
            float4 a = ah4[lane + i * 64];
            float4 w = wa4[lane + i * 64];
            acc += fast_tanh(x.x + a.x) * w.x;
            acc += fast_tanh(x.y + a.y) * w.y;
            acc += fast_tanh(x.z + a.z) * w.z;
            acc += fast_tanh(x.w + a.w) * w.w;
        }
        acc = waveReduceSum(acc);
        if (lane == 0) {
            float e = __expf(fminf(acc, 60.f));    // paranoia clamp; scores are O(1)
            weights[sidx] = e;
            esum += e;
        }
    }
    if (lane == 0 && esum != 0.f) atomicAdd(&blksum, esum);
    __syncthreads();
    if (threadIdx.x == 0 && blksum != 0.f) atomicAdd(&sums[b], blksum);
}

// ---------------- Kernel 3: att_res[b,r] = (1/T_b) * sum_s w[b,s] * att_feats[b,s,r] --
__global__ __launch_bounds__(256) void k_wsum(
    const float* __restrict__ feats, const float* __restrict__ weights,
    const float* __restrict__ sums, float* __restrict__ out)
{
    const int b  = blockIdx.x >> 5;   // SC = 32
    const int sc = blockIdx.x & 31;
    const int s0 = sc * SCHUNK;
    __shared__ float wsh[SCHUNK];
    if (threadIdx.x < SCHUNK) wsh[threadIdx.x] = weights[b * NS + s0 + threadIdx.x];
    __syncthreads();
    const float invT = 1.0f / sums[b];
    const float4* f4 = (const float4*)(feats + ((size_t)b * NS + s0) * NR);
    float4 acc = make_float4(0.f, 0.f, 0.f, 0.f);
    for (int s = 0; s < SCHUNK; ++s) {
        float w = wsh[s];
        if (w != 0.f) {               // wave-uniform skip: masked rows never fetched
            float4 v = f4[(size_t)s * 256 + threadIdx.x];
            acc.x += w * v.x; acc.y += w * v.y; acc.z += w * v.z; acc.w += w * v.w;
        }
    }
    float* o = out + b * NR + threadIdx.x * 4;
    atomicAdd(o + 0, acc.x * invT);
    atomicAdd(o + 1, acc.y * invT);
    atomicAdd(o + 2, acc.z * invT);
    atomicAdd(o + 3, acc.w * invT);
}

extern "C" void kernel_launch(void* const* d_in, const int* in_sizes, int n_in,
                              void* d_out, int out_size, void* d_ws, size_t ws_size,
                              hipStream_t stream) {
    const float* h        = (const float*)d_in[0];
    const float* feats    = (const float*)d_in[1];
    const float* p        = (const float*)d_in[2];
    const int*   masks    = (const int*)d_in[3];
    const float* W        = (const float*)d_in[4];
    const float* bh       = (const float*)d_in[5];
    const float* w_alpha  = (const float*)d_in[6];
    // d_in[7] = b_alpha: cancels in softmax renormalization — unused.
    float* out = (float*)d_out;

    float* ws      = (float*)d_ws;
    float* att_h   = ws;                         // NB*NH   = 32768 floats
    float* weights = att_h + NB * NH;            // NB*NS   = 131072 floats
    float* sums    = weights + NB * NS;          // NB      = 64 floats

    hipMemsetAsync(d_out, 0, (size_t)out_size * sizeof(float), stream);
    hipMemsetAsync(sums, 0, NB * sizeof(float), stream);

    k_atth<<<NH, 256, 0, stream>>>(h, W, bh, att_h);
    k_scores<<<NB * (NS / 16), 256, 0, stream>>>(p, att_h, w_alpha, masks, weights, sums);
    k_wsum<<<NB * SC, 256, 0, stream>>>(feats, weights, sums, out);
}

// Round 3
// 814.452 us; speedup vs baseline: 1.0238x; 1.0238x over previous
//
#include <hip/hip_runtime.h>
#include <cstdint>
#include <cmath>

#define NB 64
#define NS 2048
#define NR 1024
#define NH 512
#define SC 32              // s-chunks in weighted-sum kernel
#define SCHUNK (NS / SC)   // 64

__device__ __forceinline__ float waveReduceSum(float v) {
    #pragma unroll
    for (int off = 32; off > 0; off >>= 1) v += __shfl_down(v, off, 64);
    return v;
}

__device__ __forceinline__ float fast_tanh(float x) {
    // tanh(x) = (e^{2x}-1)/(e^{2x}+1); clamp so exp never overflows.
    float cx = fminf(fmaxf(x, -15.f), 15.f);
    float e = __expf(2.f * cx);
    return __fdividef(e - 1.f, e + 1.f);
}

// ---------------- Kernel 1: att_h[b,o] = sum_k h[b,k]*W[o,k] + bias[o] ----------------
// Also zeroes sums[] (block 0), replacing a separate memset dispatch.
__global__ __launch_bounds__(256) void k_atth(
    const float* __restrict__ h, const float* __restrict__ W,
    const float* __restrict__ bias, float* __restrict__ att_h,
    float* __restrict__ sums)
{
    const int o = blockIdx.x;  // 0..NH-1
    if (o == 0 && threadIdx.x < NB) sums[threadIdx.x] = 0.f;
    __shared__ float wsh[NR];
    for (int i = threadIdx.x; i < NR; i += 256) wsh[i] = W[(size_t)o * NR + i];
    __syncthreads();
    const int wave = threadIdx.x >> 6, lane = threadIdx.x & 63;
    const float4* w4 = (const float4*)wsh;
    const float bo = bias[o];
    for (int b = wave; b < NB; b += 4) {
        const float4* h4 = (const float4*)(h + (size_t)b * NR);
        float acc = 0.f;
        #pragma unroll
        for (int i = 0; i < NR / 4 / 64; ++i) {  // 4 iters
            float4 a = h4[lane + i * 64];
            float4 w = w4[lane + i * 64];
            acc += a.x * w.x + a.y * w.y + a.z * w.z + a.w * w.w;
        }
        acc = waveReduceSum(acc);
        if (lane == 0) att_h[b * NH + o] = acc + bo;
    }
}

// ---------------- Kernel 2: unnormalized masked-softmax weights + per-batch sum -------
// b_alpha cancels in the softmax ratio; scores are O(1), so no max-subtraction needed.
// Mask compaction up front -> branch-free row loop (loads can pipeline).
__global__ __launch_bounds__(256) void k_scores(
    const float* __restrict__ p, const float* __restrict__ att_h,
    const float* __restrict__ w_alpha,
    const int* __restrict__ masks, float* __restrict__ weights,
    float* __restrict__ sums)
{
    const int b = blockIdx.x >> 7;                 // 128 blocks per batch
    const int s_base = (blockIdx.x & 127) << 4;    // 16 s-rows per block
    const int wave = threadIdx.x >> 6, lane = threadIdx.x & 63;
    __shared__ float ah[NH], wa[NH];
    __shared__ int cidx[16];
    __shared__ int nnz_s;
    __shared__ float blksum;
    if (threadIdx.x == 0) blksum = 0.f;
    for (int i = threadIdx.x; i < NH; i += 256) {
        ah[i] = att_h[b * NH + i];
        wa[i] = w_alpha[i];
    }
    // compact non-masked rows (wave 0 only)
    if (threadIdx.x < 64) {
        bool on = false;
        if (threadIdx.x < 16) on = (masks[b * NS + s_base + threadIdx.x] != 0);
        unsigned long long m = __ballot(on);
        if (threadIdx.x < 16) {
            if (on) {
                int my = (int)__popcll(m & ((1ull << threadIdx.x) - 1ull));
                cidx[my] = threadIdx.x;
            } else {
                weights[b * NS + s_base + threadIdx.x] = 0.f;
            }
        }
        if (threadIdx.x == 0) nnz_s = (int)__popcll(m);
    }
    __syncthreads();
    const int nnz = nnz_s;
    const float4* ah4 = (const float4*)ah;
    const float4* wa4 = (const float4*)wa;
    float esum = 0.f;
    for (int i = wave; i < nnz; i += 4) {          // branch-free body
        const int s = s_base + cidx[i];
        const int sidx = b * NS + s;
        const float4* p4 = (const float4*)(p + (size_t)sidx * NH);
        float4 x0 = p4[lane];
        float4 x1 = p4[lane + 64];
        float4 a0 = ah4[lane],      a1 = ah4[lane + 64];
        float4 w0 = wa4[lane],      w1 = wa4[lane + 64];
        float acc = 0.f;
        acc += fast_tanh(x0.x + a0.x) * w0.x;
        acc += fast_tanh(x0.y + a0.y) * w0.y;
        acc += fast_tanh(x0.z + a0.z) * w0.z;
        acc += fast_tanh(x0.w + a0.w) * w0.w;
        acc += fast_tanh(x1.x + a1.x) * w1.x;
        acc += fast_tanh(x1.y + a1.y) * w1.y;
        acc += fast_tanh(x1.z + a1.z) * w1.z;
        acc += fast_tanh(x1.w + a1.w) * w1.w;
        acc = waveReduceSum(acc);
        if (lane == 0) {
            float e = __expf(fminf(acc, 60.f));    // paranoia clamp; scores are O(1)
            weights[sidx] = e;
            esum += e;
        }
    }
    if (lane == 0 && esum != 0.f) atomicAdd(&blksum, esum);
    __syncthreads();
    if (threadIdx.x == 0 && blksum != 0.f) atomicAdd(&sums[b], blksum);
}

// ---------------- Kernel 3: att_res[b,r] = (1/T_b) * sum_s w[b,s] * att_feats[b,s,r] --
// Weight compaction -> branch-free, 4 independent HBM loads in flight per wave.
__global__ __launch_bounds__(256) void k_wsum(
    const float* __restrict__ feats, const float* __restrict__ weights,
    const float* __restrict__ sums, float* __restrict__ out)
{
    const int b  = blockIdx.x >> 5;   // SC = 32
    const int sc = blockIdx.x & 31;
    const int s0 = sc * SCHUNK;
    __shared__ float cw[SCHUNK];
    __shared__ int   cidx[SCHUNK];
    __shared__ int   nnz_s;
    if (threadIdx.x < 64) {
        float w = weights[b * NS + s0 + threadIdx.x];
        unsigned long long m = __ballot(w != 0.f);
        if (w != 0.f) {
            int my = (int)__popcll(m & ((1ull << threadIdx.x) - 1ull));
            cw[my] = w; cidx[my] = threadIdx.x;
        }
        if (threadIdx.x == 0) nnz_s = (int)__popcll(m);
    }
    __syncthreads();
    const int nnz = nnz_s;
    const float invT = 1.0f / sums[b];
    const float4* f4 = (const float4*)(feats + ((size_t)b * NS + s0) * NR);
    float4 acc = make_float4(0.f, 0.f, 0.f, 0.f);
    int i = 0;
    for (; i + 4 <= nnz; i += 4) {
        const float w0 = cw[i], w1 = cw[i + 1], w2 = cw[i + 2], w3 = cw[i + 3];
        const float4 v0 = f4[(size_t)cidx[i    ] * 256 + threadIdx.x];
        const float4 v1 = f4[(size_t)cidx[i + 1] * 256 + threadIdx.x];
        const float4 v2 = f4[(size_t)cidx[i + 2] * 256 + threadIdx.x];
        const float4 v3 = f4[(size_t)cidx[i + 3] * 256 + threadIdx.x];
        acc.x += w0 * v0.x + w1 * v1.x + w2 * v2.x + w3 * v3.x;
        acc.y += w0 * v0.y + w1 * v1.y + w2 * v2.y + w3 * v3.y;
        acc.z += w0 * v0.z + w1 * v1.z + w2 * v2.z + w3 * v3.z;
        acc.w += w0 * v0.w + w1 * v1.w + w2 * v2.w + w3 * v3.w;
    }
    for (; i < nnz; ++i) {
        const float w = cw[i];
        const float4 v = f4[(size_t)cidx[i] * 256 + threadIdx.x];
        acc.x += w * v.x; acc.y += w * v.y; acc.z += w * v.z; acc.w += w * v.w;
    }
    float* o = out + b * NR + threadIdx.x * 4;
    atomicAdd(o + 0, acc.x * invT);
    atomicAdd(o + 1, acc.y * invT);
    atomicAdd(o + 2, acc.z * invT);
    atomicAdd(o + 3, acc.w * invT);
}

extern "C" void kernel_launch(void* const* d_in, const int* in_sizes, int n_in,
                              void* d_out, int out_size, void* d_ws, size_t ws_size,
                              hipStream_t stream) {
    const float* h        = (const float*)d_in[0];
    const float* feats    = (const float*)d_in[1];
    const float* p        = (const float*)d_in[2];
    const int*   masks    = (const int*)d_in[3];
    const float* W        = (const float*)d_in[4];
    const float* bh       = (const float*)d_in[5];
    const float* w_alpha  = (const float*)d_in[6];
    // d_in[7] = b_alpha: cancels in softmax renormalization — unused.
    float* out = (float*)d_out;

    float* ws      = (float*)d_ws;
    float* att_h   = ws;                         // NB*NH   = 32768 floats
    float* weights = att_h + NB * NH;            // NB*NS   = 131072 floats
    float* sums    = weights + NB * NS;          // NB      = 64 floats

    hipMemsetAsync(d_out, 0, (size_t)out_size * sizeof(float), stream);

    k_atth<<<NH, 256, 0, stream>>>(h, W, bh, att_h, sums);
    k_scores<<<NB * (NS / 16), 256, 0, stream>>>(p, att_h, w_alpha, masks, weights, sums);
    k_wsum<<<NB * SC, 256, 0, stream>>>(feats, weights, sums, out);
}